// Round 9
// baseline (262.147 us; speedup 1.0000x reference)
//
#include <hip/hip_runtime.h>
#include <math.h>

#define BATCH 4
#define SEQ   2048
#define DMODEL 1024
#define HEADS 16
#define DHEAD 64
#define SCALE 0.03125f                 // DIM^-0.5 = 1/32
#define KEXP  0.045084220027780106f    // SCALE * log2(e)
#define QKV_ELEMS (BATCH * HEADS * SEQ * DHEAD)  // 8388608 per tensor

typedef __attribute__((ext_vector_type(8))) short short8;
typedef __attribute__((ext_vector_type(4))) float floatx4;
typedef unsigned int u32;

__device__ __forceinline__ unsigned short f2bf(float f) {
  union { float f; unsigned u; } v;
  v.f = f;
  return (unsigned short)((v.u + 0x7FFFu + ((v.u >> 16) & 1u)) >> 16);
}

__device__ __forceinline__ float fast_exp2(float x) {
#if __has_builtin(__builtin_amdgcn_exp2f)
  return __builtin_amdgcn_exp2f(x);
#else
  return __expf(x * 0.6931471805599453f);
#endif
}

// pack two fp32 -> bf16x2 in one u32 (low = p0, high = p1)
__device__ __forceinline__ u32 pack_bf16(float p0, float p1) {
#if __has_builtin(__builtin_amdgcn_cvt_pk_bf16_f32)
  typedef __bf16 bf16x2 __attribute__((ext_vector_type(2)));
  bf16x2 t = __builtin_amdgcn_cvt_pk_bf16_f32(p0, p1);
  u32 r;
  __builtin_memcpy(&r, &t, 4);
  return r;
#else
  u32 a0 = __float_as_uint(p0) + 0x8000u;
  u32 a1 = __float_as_uint(p1) + 0x8000u;
  return __builtin_amdgcn_perm(a1, a0, 0x07060302);
#endif
}

// async global->LDS, 16B per lane; lds dest is wave-uniform base + lane*16.
__device__ __forceinline__ void async_ld16(const void* g, void* l) {
  __builtin_amdgcn_global_load_lds(
      (const __attribute__((address_space(1))) u32*)g,
      (__attribute__((address_space(3))) u32*)l, 16, 0, 0);
}

// ---------------------------------------------------------------------------
// Merged prep: x->bf16 (blocks 0..8191), wqkv transpose (8192..11263),
// wout transpose (11264..12287).
// ---------------------------------------------------------------------------
__device__ __forceinline__ void trans_tile(const float* __restrict__ W,
                                           unsigned short* __restrict__ WT,
                                           int K, int N, int n0, int k0,
                                           float (*tile)[33]) {
  const int tx = threadIdx.x & 31, ty = threadIdx.x >> 5;  // ty 0..7
#pragma unroll
  for (int i = 0; i < 4; ++i)
    tile[ty + i * 8][tx] = W[(size_t)(k0 + ty + i * 8) * N + n0 + tx];
  __syncthreads();
#pragma unroll
  for (int i = 0; i < 4; ++i)
    WT[(size_t)(n0 + ty + i * 8) * K + k0 + tx] = f2bf(tile[tx][ty + i * 8]);
}

__global__ __launch_bounds__(256) void prep_kernel(
    const float* __restrict__ x, const float* __restrict__ wqkv,
    const float* __restrict__ wout, unsigned short* __restrict__ xb,
    unsigned short* __restrict__ wqkvT, unsigned short* __restrict__ woutT) {
  __shared__ float tile[32][33];
  const int bx = blockIdx.x;
  if (bx < 8192) {
    size_t i = ((size_t)bx * 256 + threadIdx.x) * 4;
    float4 v = *(const float4*)(x + i);
    ushort4 o;
    o.x = f2bf(v.x); o.y = f2bf(v.y); o.z = f2bf(v.z); o.w = f2bf(v.w);
    *(ushort4*)(xb + i) = o;
  } else if (bx < 11264) {
    int t = bx - 8192;
    trans_tile(wqkv, wqkvT, 1024, 3072, (t % 96) * 32, (t / 96) * 32, tile);
  } else {
    int t = bx - 11264;
    trans_tile(wout, woutT, 1024, 1024, (t % 32) * 32, (t / 32) * 32, tile);
  }
}

// ---------------------------------------------------------------------------
// GEMM core: A[M][1024] bf16 @ BT[N][1024]^T, 128x128 tile, BK=64, async
// global_load_lds staging with XOR d-block swizzle (conflict-free frag reads).
// ---------------------------------------------------------------------------
__device__ __forceinline__ void gemm_core(
    const unsigned short* __restrict__ A, const unsigned short* __restrict__ BT,
    unsigned short* As, unsigned short* Bs, int m0, int n0,
    floatx4 acc[4][4]) {
  const int tid = threadIdx.x;
  const int wave = tid >> 6, lane = tid & 63;
  const int quad = lane >> 4, l16 = lane & 15;
  const int wm = wave >> 1, wn = wave & 1;
  const int lrow = lane >> 3, ls = lane & 7;
  const int dblk = ls ^ (lrow & 7);
  const int sw = l16 & 7;

#pragma unroll
  for (int mt = 0; mt < 4; ++mt)
#pragma unroll
    for (int nt = 0; nt < 4; ++nt) acc[mt][nt] = (floatx4){0.f, 0.f, 0.f, 0.f};

  for (int k0 = 0; k0 < DMODEL; k0 += 64) {
    __syncthreads();
#pragma unroll
    for (int i = 0; i < 4; ++i) {
      int chunk = wave * 4 + i;
      int row = chunk * 8 + lrow;
      async_ld16(A + (size_t)(m0 + row) * DMODEL + k0 + dblk * 8,
                 As + chunk * 512);
      async_ld16(BT + (size_t)(n0 + row) * DMODEL + k0 + dblk * 8,
                 Bs + chunk * 512);
    }
    __syncthreads();
#pragma unroll
    for (int kk = 0; kk < 64; kk += 32) {
      const int kb = kk >> 3;  // 0 or 4
      short8 a[4], b[4];
#pragma unroll
      for (int t = 0; t < 4; ++t) {
        int row = wm * 64 + t * 16 + l16;
        a[t] = *(short8*)(As + row * 64 + (((kb + quad) ^ sw) * 8));
        int rowb = wn * 64 + t * 16 + l16;
        b[t] = *(short8*)(Bs + rowb * 64 + (((kb + quad) ^ sw) * 8));
      }
#pragma unroll
      for (int mt = 0; mt < 4; ++mt)
#pragma unroll
        for (int nt = 0; nt < 4; ++nt)
          acc[mt][nt] = __builtin_amdgcn_mfma_f32_16x16x32_bf16(
              a[mt], b[nt], acc[mt][nt], 0, 0, 0);
    }
  }
}

// ---------------------------------------------------------------------------
// GEMM1: n-blocks 0..7 -> Q (pre-scaled by KEXP), 8..15 -> K, both repacked
// through LDS into coalesced 128B token-head rows of [B,H,N,64];
// n-blocks 16..23 -> V transposed via LDS into vtg [B,H,64,N'] (pc-permuted).
// ---------------------------------------------------------------------------
__global__ __launch_bounds__(256) void gemm_qkv_kernel(
    const unsigned short* __restrict__ A, const unsigned short* __restrict__ BT,
    unsigned short* __restrict__ qk, unsigned short* __restrict__ vtg) {
  __shared__ __align__(16) unsigned char smem[128 * 136 * 2];  // 34816 B
  unsigned short* As = (unsigned short*)smem;            // 128*64
  unsigned short* Bs = As + 128 * 64;                    // 128*64
  unsigned short* T = (unsigned short*)smem;             // reused for repack
  const int tid = threadIdx.x;
  const int wave = tid >> 6, lane = tid & 63;
  const int quad = lane >> 4, l16 = lane & 15;
  const int wm = wave >> 1, wn = wave & 1;
  const int m0 = blockIdx.y * 128, n0 = blockIdx.x * 128;
  floatx4 acc[4][4];
  gemm_core(A, BT, As, Bs, m0, n0, acc);

  const int b = m0 >> 11, ntok = m0 & 2047;
  __syncthreads();  // done reading As/Bs

  if (blockIdx.x < 16) {
    // Q/K: repack into T[token][c] (stride 132), coalesced 128B row stores.
    const float qsc = (blockIdx.x < 8) ? KEXP : 1.0f;
#pragma unroll
    for (int mt = 0; mt < 4; ++mt) {
#pragma unroll
      for (int nt = 0; nt < 4; ++nt) {
        int c = wn * 64 + nt * 16 + l16;
#pragma unroll
        for (int r = 0; r < 4; ++r) {
          int mloc = wm * 64 + mt * 16 + quad * 4 + r;
          T[mloc * 132 + c] = f2bf(acc[mt][nt][r] * qsc);
        }
      }
    }
    __syncthreads();
    const int which = blockIdx.x >> 3;
    const int h0 = (n0 >> 6) & 15;
    const int inner = tid & 7;
#pragma unroll
    for (int pass = 0; pass < 8; ++pass) {
      int row = pass * 32 + (tid >> 3);
      int token = row >> 1, hh = row & 1;
      *(short8*)(qk + (size_t)which * QKV_ELEMS +
                 (((size_t)((b * HEADS + h0 + hh) * SEQ + ntok + token)) << 6) +
                 inner * 8) = *(short8*)&T[token * 132 + hh * 64 + inner * 8];
    }
  } else {
    // V: transpose through LDS with pc-permutation, 16B stores along tokens.
#pragma unroll
    for (int mt = 0; mt < 4; ++mt) {
#pragma unroll
      for (int nt = 0; nt < 4; ++nt) {
        int c = wn * 64 + nt * 16 + l16;
#pragma unroll
        for (int r = 0; r < 4; ++r) {
          int mloc = wm * 64 + mt * 16 + quad * 4 + r;
          int pcm = (mloc & ~31) | ((mloc & 15) << 1) | ((mloc >> 4) & 1);
          T[c * 136 + pcm] = f2bf(acc[mt][nt][r]);
        }
      }
    }
    __syncthreads();
    const int c = tid >> 1, hh = tid & 1;
    const int nc = n0 - 2048 + c;  // v-column 0..1023
    const int h = nc >> 6, d = nc & 63;
    const size_t dstbase =
        (((size_t)(b * HEADS + h)) * DHEAD + d) * SEQ + ntok;
#pragma unroll
    for (int j = 0; j < 8; ++j) {
      int t0 = (2 * j + hh) * 8;
      *(short8*)(vtg + dstbase + t0) = *(short8*)&T[c * 136 + t0];
    }
  }
}

__global__ __launch_bounds__(256) void gemm_out_kernel(
    const unsigned short* __restrict__ A, const unsigned short* __restrict__ BT,
    const float* __restrict__ bias, float* __restrict__ C) {
  __shared__ __align__(16) unsigned short As[128 * 64];
  __shared__ __align__(16) unsigned short Bs[128 * 64];
  const int tid = threadIdx.x;
  const int wave = tid >> 6, lane = tid & 63;
  const int quad = lane >> 4, l16 = lane & 15;
  const int wm = wave >> 1, wn = wave & 1;
  const int m0 = blockIdx.y * 128, n0 = blockIdx.x * 128;
  floatx4 acc[4][4];
  gemm_core(A, BT, As, Bs, m0, n0, acc);

#pragma unroll
  for (int mt = 0; mt < 4; ++mt) {
#pragma unroll
    for (int nt = 0; nt < 4; ++nt) {
      int nc = n0 + wn * 64 + nt * 16 + l16;
      float bv = bias[nc];
#pragma unroll
      for (int r = 0; r < 4; ++r) {
        int m = m0 + wm * 64 + mt * 16 + quad * 4 + r;
        C[(size_t)m * DMODEL + nc] = acc[mt][nt][r] + bv;
      }
    }
  }
}

// ---------------------------------------------------------------------------
// Flash attention. Block = (bh, 128-query tile); wave = 32 q (2 subtiles).
// Private P slot per (qs, kc2) -> the four exp->PV chains per 64-key tile
// are independent (no LDS write-after-read serialization); single-buffer K/V
// (dbuf measured neutral in R8). Q pre-scaled by KEXP; denominator via
// ones-MFMA; XCD-aware bh swizzle.
// ---------------------------------------------------------------------------
__global__ __launch_bounds__(256, 4) void attn_kernel(
    const unsigned short* __restrict__ Qb, const unsigned short* __restrict__ Kb,
    const unsigned short* __restrict__ Vtg, unsigned short* __restrict__ Op) {
  __shared__ __align__(16) unsigned short Ks[64 * 64];
  __shared__ __align__(16) unsigned short Vs[64 * 64];
  __shared__ __align__(16) unsigned short Pl[4][2][2][16][40];  // 20.5 KB
  const int tid = threadIdx.x;
  const int wave = tid >> 6, lane = tid & 63;
  const int quad = lane >> 4, l16 = lane & 15;
  const int bh = blockIdx.x & 63, qt = blockIdx.x >> 6;
  const size_t base = (size_t)bh * SEQ * DHEAD;
  const int lrow = lane >> 3, ls = lane & 7;
  const int dblk = ls ^ (lrow & 7);
  const int sw = l16 & 7;

  const unsigned short* kbase = Kb + base;
  const unsigned short* vbase = Vtg + base;

  short8 onesf;
#pragma unroll
  for (int i = 0; i < 8; ++i) onesf[i] = (short)0x3F80;  // bf16 1.0

  short8 qf[2][2];
#pragma unroll
  for (int qs = 0; qs < 2; ++qs) {
    int qrow = qt * 128 + wave * 32 + qs * 16 + l16;
    qf[qs][0] = *(const short8*)(Qb + base + (size_t)qrow * DHEAD + quad * 8);
    qf[qs][1] =
        *(const short8*)(Qb + base + (size_t)qrow * DHEAD + 32 + quad * 8);
  }

  floatx4 o[2][4], lacc[2];
#pragma unroll
  for (int qs = 0; qs < 2; ++qs) {
    lacc[qs] = (floatx4){0.f, 0.f, 0.f, 0.f};
#pragma unroll
    for (int dt = 0; dt < 4; ++dt) o[qs][dt] = (floatx4){0.f, 0.f, 0.f, 0.f};
  }

  for (int kc = 0; kc < SEQ / 64; ++kc) {
    __syncthreads();
#pragma unroll
    for (int i = 0; i < 2; ++i) {
      int c = wave * 2 + i;
      int row = c * 8 + lrow;
      async_ld16(kbase + (size_t)(kc * 64 + row) * DHEAD + dblk * 8,
                 Ks + c * 512);
      async_ld16(vbase + (size_t)row * SEQ + kc * 64 + dblk * 8, Vs + c * 512);
    }
    __syncthreads();

#pragma unroll
    for (int kc2 = 0; kc2 < 2; ++kc2) {
      const int krow = kc2 * 32;
      // K fragments for this 32-key half
      short8 kf00 = *(short8*)(Ks + (krow + l16) * 64 + ((quad ^ sw) * 8));
      short8 kf01 = *(short8*)(Ks + (krow + l16) * 64 + (((4 + quad) ^ sw) * 8));
      short8 kf10 = *(short8*)(Ks + (krow + 16 + l16) * 64 + ((quad ^ sw) * 8));
      short8 kf11 =
          *(short8*)(Ks + (krow + 16 + l16) * 64 + (((4 + quad) ^ sw) * 8));
      // S for BOTH q-subtiles first (8 independent MFMAs)
      floatx4 s[2][2];
#pragma unroll
      for (int qs = 0; qs < 2; ++qs) {
        s[qs][0] = (floatx4){0.f, 0.f, 0.f, 0.f};
        s[qs][1] = (floatx4){0.f, 0.f, 0.f, 0.f};
        s[qs][0] = __builtin_amdgcn_mfma_f32_16x16x32_bf16(qf[qs][0], kf00,
                                                           s[qs][0], 0, 0, 0);
        s[qs][1] = __builtin_amdgcn_mfma_f32_16x16x32_bf16(qf[qs][0], kf10,
                                                           s[qs][1], 0, 0, 0);
        s[qs][0] = __builtin_amdgcn_mfma_f32_16x16x32_bf16(qf[qs][1], kf01,
                                                           s[qs][0], 0, 0, 0);
        s[qs][1] = __builtin_amdgcn_mfma_f32_16x16x32_bf16(qf[qs][1], kf11,
                                                           s[qs][1], 0, 0, 0);
      }
      // V fragments (independent of S/exp)
      short8 vf[4];
#pragma unroll
      for (int dt = 0; dt < 4; ++dt)
        vf[dt] = *(short8*)(Vs + (dt * 16 + l16) * 64 +
                            (((kc2 * 4 + quad) ^ sw) * 8));
      // exp + pack into PRIVATE (qs,kc2) slots
#pragma unroll
      for (int qs = 0; qs < 2; ++qs) {
#pragma unroll
        for (int r = 0; r < 4; ++r) {
          float p0 = fast_exp2(s[qs][0][r]);
          float p1 = fast_exp2(s[qs][1][r]);
          *(u32*)&Pl[wave][qs][kc2][quad * 4 + r][2 * l16] = pack_bf16(p0, p1);
        }
      }
      // PV + denominator
#pragma unroll
      for (int qs = 0; qs < 2; ++qs) {
        short8 pf = *(short8*)&Pl[wave][qs][kc2][l16][quad * 8];
        lacc[qs] =
            __builtin_amdgcn_mfma_f32_16x16x32_bf16(pf, onesf, lacc[qs], 0, 0, 0);
#pragma unroll
        for (int dt = 0; dt < 4; ++dt)
          o[qs][dt] = __builtin_amdgcn_mfma_f32_16x16x32_bf16(pf, vf[dt],
                                                              o[qs][dt], 0, 0, 0);
      }
    }
  }

  const int b = bh >> 4, h = bh & 15;
#pragma unroll
  for (int qs = 0; qs < 2; ++qs) {
#pragma unroll
    for (int r = 0; r < 4; ++r) {
      float inv = 1.f / lacc[qs][r];
      int n = qt * 128 + wave * 32 + qs * 16 + quad * 4 + r;
      size_t rowbase = ((size_t)(b * SEQ + n)) * DMODEL + h * DHEAD;
#pragma unroll
      for (int dt = 0; dt < 4; ++dt)
        Op[rowbase + dt * 16 + l16] = f2bf(o[qs][dt][r] * inv);
    }
  }
}

extern "C" void kernel_launch(void* const* d_in, const int* in_sizes, int n_in,
                              void* d_out, int out_size, void* d_ws,
                              size_t ws_size, hipStream_t stream) {
  const float* x = (const float*)d_in[0];
  const float* w_qkv = (const float*)d_in[1];
  const float* w_out = (const float*)d_in[2];
  const float* b_out = (const float*)d_in[3];
  float* out = (float*)d_out;

  unsigned short* ws = (unsigned short*)d_ws;
  unsigned short* xb = ws;                         // 8388608
  unsigned short* wqkvT = xb + 8388608;            // 3145728  [3072][1024]
  unsigned short* woutT = wqkvT + 3145728;         // 1048576  [1024][1024]
  unsigned short* qb = woutT + 1048576;            // [B,H,N,64] (pre-scaled)
  unsigned short* kb = qb + QKV_ELEMS;             // [B,H,N,64]
  unsigned short* vtg = kb + QKV_ELEMS;            // [B,H,64,N] permuted cols
  unsigned short* op = vtg + QKV_ELEMS;            // [B,N,1024]

  prep_kernel<<<dim3(12288), dim3(256), 0, stream>>>(x, w_qkv, w_out, xb,
                                                     wqkvT, woutT);
  gemm_qkv_kernel<<<dim3(24, 64), dim3(256), 0, stream>>>(xb, wqkvT, qb, vtg);
  attn_kernel<<<dim3(1024), dim3(256), 0, stream>>>(qb, kb, vtg, op);
  gemm_out_kernel<<<dim3(8, 64), dim3(256), 0, stream>>>(op, woutT, b_out, out);
}